// Round 1
// baseline (588.418 us; speedup 1.0000x reference)
//
#include <hip/hip_runtime.h>
#include <hip/hip_cooperative_groups.h>

#define H 1024
#define V 50257
#define L 50

namespace cg = cooperative_groups;

// ---------------------------------------------------------------------------
// Design: the whole decode step is a strictly serial chain of tiny stages.
// Previous version = 8 serialized dispatches; rocprof shows the work itself
// is only ~40-70 us of BW-bound time, so dispatch boundaries dominate.
// This version = ONE cooperative kernel, 256 blocks x 512 threads
// (1 block/CU guaranteed: 17.5 KB LDS, <=256 VGPR via __launch_bounds__),
// 6 grid.sync()s. Per-dot accumulation order is kept identical to the
// verified legacy kernels to minimize numeric drift.
// ---------------------------------------------------------------------------

__device__ __forceinline__ float wave_reduce(float v) {
    #pragma unroll
    for (int off = 32; off; off >>= 1) v += __shfl_down(v, off);
    return v;
}

__device__ __forceinline__ float dot4(float4 a, float4 b) {
    return a.x * b.x + a.y * b.y + a.z * b.z + a.w * b.w;
}

struct FusedArgs {
    const int*   input_ids;
    const float* hidden;
    const float* enc;
    const float* emb;
    const float* attn_w;
    const float* attn_b;
    const float* comb_w;
    const float* comb_b;
    const float* w_ih;
    const float* w_hh;
    const float* b_ih;
    const float* b_hh;
    const float* out_w;
    const float* out_b;
    float*       out;   // [V | H | L]
    float*       ws;
};

__global__ void __launch_bounds__(512, 2) fused_kernel(FusedArgs a) {
    __shared__ __align__(16) float s_c[2 * H];   // comb concat [emb | applied]
    __shared__ __align__(16) float s_x[H];       // GRU x
    __shared__ __align__(16) float s_h[H];       // GRU h_prev
    __shared__ float s_g[4][6];                  // GRU gate partials per row
    __shared__ float s_part[8];                  // per-wave partials
    __shared__ float s_red[256];                 // lse block reduce

    cg::grid_group grid = cg::this_grid();
    const int tid  = threadIdx.x;                // 512
    const int bid  = blockIdx.x;                 // 256
    const int wave = tid >> 6, lane = tid & 63;

    float* ws_scores = a.ws;                     // 64
    float* ws_app    = a.ws + 64;                // H
    float* ws_x1     = ws_app + H;               // H
    float* ws_h1     = ws_x1 + H;                // H
    float* ws_x2     = ws_h1 + H;                // H
    float* ws_h2     = ws_x2 + H;                // H
    float* ws_part   = ws_h2 + H;                // 256

    const int token = a.input_ids[0];

    // ---- P1: attention scores (blocks 0..49, one l each) -------------------
    if (bid < L) {
        float4 aw = ((const float4*)(a.attn_w + (size_t)bid * 2 * H))[tid];
        float4 xv = (tid < 256) ? ((const float4*)(a.emb + (size_t)token * H))[tid]
                                : ((const float4*)a.hidden)[tid - 256];
        float acc = wave_reduce(dot4(aw, xv));
        if (lane == 0) s_part[wave] = acc;
        __syncthreads();
        if (tid == 0) {
            float s = 0.f;
            #pragma unroll
            for (int w = 0; w < 8; ++w) s += s_part[w];
            ws_scores[bid] = s + a.attn_b[bid];
        }
    }
    grid.sync();   // #1

    // ---- P2: softmax (redundant per thread) + applied (blocks 0..1) --------
    if (bid < 2) {
        const int j = bid * 512 + tid;           // 0..1023
        float m = ws_scores[0];
        #pragma unroll
        for (int l = 1; l < L; ++l) m = fmaxf(m, ws_scores[l]);
        float ssum = 0.f;
        #pragma unroll
        for (int l = 0; l < L; ++l) ssum += expf(ws_scores[l] - m);
        float inv = 1.f / ssum;
        float acc = 0.f;
        #pragma unroll
        for (int l = 0; l < L; ++l) {
            float wl = expf(ws_scores[l] - m);
            wl *= inv;
            acc += wl * a.enc[l * H + j];
        }
        ws_app[j] = acc;
        if (bid == 0 && tid < L) {
            float wl = expf(ws_scores[tid] - m);
            a.out[V + H + tid] = wl * inv;
        }
    }
    grid.sync();   // #2

    // ---- P3: comb matvec (1024 rows, wave-per-row, waves 0..3) + relu ------
    if (tid < 256) ((float4*)s_c)[tid]           = ((const float4*)(a.emb + (size_t)token * H))[tid];
    else           ((float4*)(s_c + H))[tid - 256] = ((const float4*)ws_app)[tid - 256];
    __syncthreads();
    if (wave < 4) {
        const int i = bid * 4 + wave;            // 0..1023
        const float4* r4 = (const float4*)(a.comb_w + (size_t)i * 2 * H);
        const float4* c4 = (const float4*)s_c;
        float acc = 0.f;
        #pragma unroll
        for (int kk = 0; kk < 8; ++kk) {
            int k = kk * 64 + lane;
            acc += dot4(r4[k], c4[k]);
        }
        acc = wave_reduce(acc);
        if (lane == 0) ws_x1[i] = fmaxf(acc + a.comb_b[i], 0.f);
    }
    grid.sync();   // #3

    // ---- P4/P5: GRU x2 (4 rows/block, 24 gate-dots over 8 waves) -----------
    for (int layer = 0; layer < 2; ++layer) {
        const float* xg = layer ? ws_x2 : ws_x1;
        const float* hg = layer ? ws_h1 : a.hidden;
        if (tid < 256) ((float4*)s_x)[tid]       = ((const float4*)xg)[tid];
        else           ((float4*)s_h)[tid - 256] = ((const float4*)hg)[tid - 256];
        __syncthreads();
        #pragma unroll
        for (int q = 0; q < 3; ++q) {
            const int t = wave * 3 + q;          // 0..23
            const int r = t / 6, g = t % 6;
            const int i = bid * 4 + r;
            const float4* w4 = (const float4*)((g < 3)
                ? (a.w_ih + (size_t)(g * H + i) * H)
                : (a.w_hh + (size_t)((g - 3) * H + i) * H));
            const float4* v4 = (const float4*)((g < 3) ? s_x : s_h);
            float acc = 0.f;
            #pragma unroll
            for (int kk = 0; kk < 4; ++kk) {
                int k = kk * 64 + lane;
                acc += dot4(w4[k], v4[k]);
            }
            acc = wave_reduce(acc);
            if (lane == 0) s_g[r][g] = acc;
        }
        __syncthreads();
        if (tid < 4) {
            const int r = tid, i = bid * 4 + r;
            float gxr = s_g[r][0] + a.b_ih[i];         float ghr = s_g[r][3] + a.b_hh[i];
            float gxz = s_g[r][1] + a.b_ih[H + i];     float ghz = s_g[r][4] + a.b_hh[H + i];
            float gxn = s_g[r][2] + a.b_ih[2 * H + i]; float ghn = s_g[r][5] + a.b_hh[2 * H + i];
            float rr = 1.f / (1.f + expf(-(gxr + ghr)));
            float zz = 1.f / (1.f + expf(-(gxz + ghz)));
            float nn = tanhf(gxn + rr * ghn);
            float hn = (1.f - zz) * nn + zz * s_h[i];
            if (layer == 0) { ws_h1[i] = hn; ws_x2[i] = fmaxf(hn, 0.f); }
            else            { ws_h2[i] = hn; a.out[V + i] = hn; }
        }
        grid.sync();   // #4, #5
    }

    // ---- P6: vocab logits + per-block exp partials -------------------------
    // h fragment lives in registers; 4 rows per wave, 32 rows per block-pass,
    // 8192 rows per grid-pass, 7 passes.
    {
        const float4* h4 = (const float4*)ws_h2;
        const float4 hv0 = h4[lane];
        const float4 hv1 = h4[64 + lane];
        const float4 hv2 = h4[128 + lane];
        const float4 hv3 = h4[192 + lane];
        float psum = 0.f;
        for (int pass = 0; pass < 7; ++pass) {
            const int v0 = pass * 8192 + bid * 32 + wave * 4;
            if (v0 >= V) continue;               // uniform per wave
            #pragma unroll
            for (int r = 0; r < 4; ++r) {
                const int v  = v0 + r;
                const int vc = (v < V) ? v : (V - 1);   // clamp keeps loads legal
                const float4* w4 = (const float4*)(a.out_w + (size_t)vc * H);
                float acc = 0.f;
                acc += dot4(w4[lane], hv0);
                acc += dot4(w4[64 + lane], hv1);
                acc += dot4(w4[128 + lane], hv2);
                acc += dot4(w4[192 + lane], hv3);
                acc = wave_reduce(acc);
                if (lane == 0 && v < V) {
                    float lg = acc + a.out_b[v];
                    a.out[v] = lg;
                    psum += expf(lg);
                }
            }
        }
        if (lane == 0) s_part[wave] = psum;
        __syncthreads();
        if (tid == 0) {
            float s = 0.f;
            #pragma unroll
            for (int w = 0; w < 8; ++w) s += s_part[w];
            ws_part[bid] = s;
        }
    }
    grid.sync();   // #6

    // ---- P7: redundant per-block lse reduce + log-softmax subtract ---------
    s_red[tid & 255] = 0.f;                      // benign double-store, then overwrite
    __syncthreads();
    if (tid < 256) s_red[tid] = ws_part[tid];
    __syncthreads();
    #pragma unroll
    for (int off = 128; off; off >>= 1) {
        if (tid < off) s_red[tid] += s_red[tid + off];
        __syncthreads();
    }
    const float lse = logf(s_red[0]);
    const int v = bid * 512 + tid;
    if (v < V) a.out[v] -= lse;
}

// ===========================================================================
// Legacy 8-kernel fallback (verified path) — used only if the cooperative
// launch is rejected (e.g. capture-mode incompatibility).
// ===========================================================================

__global__ void scores_kernel(const int* __restrict__ input_ids,
                              const float* __restrict__ hidden,
                              const float* __restrict__ emb,
                              const float* __restrict__ attn_w,
                              const float* __restrict__ attn_b,
                              float* __restrict__ ws_scores) {
    __shared__ float s_part[8];
    const int tid = threadIdx.x;
    const int l   = blockIdx.x;
    const int wave = tid >> 6, lane = tid & 63;
    const int token = input_ids[0];

    float4 a = ((const float4*)(attn_w + (size_t)l * 2 * H))[tid];
    float4 x = (tid < 256) ? ((const float4*)(emb + (size_t)token * H))[tid]
                           : ((const float4*)hidden)[tid - 256];
    float acc = a.x * x.x + a.y * x.y + a.z * x.z + a.w * x.w;
    #pragma unroll
    for (int off = 32; off; off >>= 1) acc += __shfl_down(acc, off);
    if (lane == 0) s_part[wave] = acc;
    __syncthreads();
    if (tid == 0) {
        float s = 0.f;
        #pragma unroll
        for (int w = 0; w < 8; ++w) s += s_part[w];
        ws_scores[l] = s + attn_b[l];
    }
}

__global__ void applied_kernel(const float* __restrict__ ws_scores,
                               const float* __restrict__ enc,
                               float* __restrict__ ws_app,
                               float* __restrict__ out_attnw) {
    const int j = blockIdx.x * 256 + threadIdx.x;
    float w[L];
    float m = ws_scores[0];
    #pragma unroll
    for (int l = 1; l < L; ++l) m = fmaxf(m, ws_scores[l]);
    float s = 0.f;
    #pragma unroll
    for (int l = 0; l < L; ++l) { w[l] = expf(ws_scores[l] - m); s += w[l]; }
    float inv = 1.f / s;
    float acc = 0.f;
    #pragma unroll
    for (int l = 0; l < L; ++l) { w[l] *= inv; acc += w[l] * enc[l * H + j]; }
    ws_app[j] = acc;
    if (blockIdx.x == 0 && threadIdx.x < L) out_attnw[threadIdx.x] = w[threadIdx.x];
}

__global__ void comb_kernel(const float* __restrict__ comb_w,
                            const float* __restrict__ comb_b,
                            const int* __restrict__ input_ids,
                            const float* __restrict__ emb,
                            const float* __restrict__ applied,
                            float* __restrict__ x1) {
    __shared__ __align__(16) float s_c[2 * H];
    const int tid = threadIdx.x;
    const int token = input_ids[0];
    ((float4*)s_c)[tid] = ((const float4*)(emb + (size_t)token * H))[tid];
    ((float4*)(s_c + H))[tid] = ((const float4*)applied)[tid];
    __syncthreads();

    const int wave = tid >> 6, lane = tid & 63;
    const int i = blockIdx.x * 4 + wave;
    const float4* r4 = (const float4*)(comb_w + (size_t)i * 2 * H);
    const float4* c4 = (const float4*)s_c;
    float acc = 0.f;
    #pragma unroll
    for (int kk = 0; kk < 8; ++kk) {
        int k = kk * 64 + lane;
        float4 a = r4[k], b = c4[k];
        acc += a.x * b.x + a.y * b.y + a.z * b.z + a.w * b.w;
    }
    #pragma unroll
    for (int off = 32; off; off >>= 1) acc += __shfl_down(acc, off);
    if (lane == 0) x1[i] = fmaxf(acc + comb_b[i], 0.f);
}

__global__ void gru_kernel(const float* __restrict__ x,
                           const float* __restrict__ hprev,
                           const float* __restrict__ w_ih,
                           const float* __restrict__ w_hh,
                           const float* __restrict__ b_ih,
                           const float* __restrict__ b_hh,
                           float* __restrict__ h_out,
                           float* __restrict__ x_out,
                           float* __restrict__ h_copy) {
    __shared__ __align__(16) float s_x[H];
    __shared__ __align__(16) float s_h[H];
    const int tid = threadIdx.x;
    ((float4*)s_x)[tid] = ((const float4*)x)[tid];
    ((float4*)s_h)[tid] = ((const float4*)hprev)[tid];
    __syncthreads();

    const int wave = tid >> 6, lane = tid & 63;
    const int i = blockIdx.x * 4 + wave;
    const float4* x4 = (const float4*)s_x;
    const float4* h4 = (const float4*)s_h;
    const float4* wr_x = (const float4*)(w_ih + (size_t)i * H);
    const float4* wz_x = (const float4*)(w_ih + (size_t)(H + i) * H);
    const float4* wn_x = (const float4*)(w_ih + (size_t)(2 * H + i) * H);
    const float4* wr_h = (const float4*)(w_hh + (size_t)i * H);
    const float4* wz_h = (const float4*)(w_hh + (size_t)(H + i) * H);
    const float4* wn_h = (const float4*)(w_hh + (size_t)(2 * H + i) * H);

    float ar = 0.f, az = 0.f, an = 0.f, br = 0.f, bz = 0.f, bn = 0.f;
    #pragma unroll
    for (int kk = 0; kk < 4; ++kk) {
        int k = kk * 64 + lane;
        float4 xv = x4[k], hv = h4[k], t;
        t = wr_x[k]; ar += t.x * xv.x + t.y * xv.y + t.z * xv.z + t.w * xv.w;
        t = wz_x[k]; az += t.x * xv.x + t.y * xv.y + t.z * xv.z + t.w * xv.w;
        t = wn_x[k]; an += t.x * xv.x + t.y * xv.y + t.z * xv.z + t.w * xv.w;
        t = wr_h[k]; br += t.x * hv.x + t.y * hv.y + t.z * hv.z + t.w * hv.w;
        t = wz_h[k]; bz += t.x * hv.x + t.y * hv.y + t.z * hv.z + t.w * hv.w;
        t = wn_h[k]; bn += t.x * hv.x + t.y * hv.y + t.z * hv.z + t.w * hv.w;
    }
    #pragma unroll
    for (int off = 32; off; off >>= 1) {
        ar += __shfl_down(ar, off); az += __shfl_down(az, off);
        an += __shfl_down(an, off); br += __shfl_down(br, off);
        bz += __shfl_down(bz, off); bn += __shfl_down(bn, off);
    }
    if (lane == 0) {
        float gxr = ar + b_ih[i],         ghr = br + b_hh[i];
        float gxz = az + b_ih[H + i],     ghz = bz + b_hh[H + i];
        float gxn = an + b_ih[2 * H + i], ghn = bn + b_hh[2 * H + i];
        float r = 1.f / (1.f + expf(-(gxr + ghr)));
        float z = 1.f / (1.f + expf(-(gxz + ghz)));
        float n = tanhf(gxn + r * ghn);
        float hn = (1.f - z) * n + z * s_h[i];
        h_out[i] = hn;
        if (x_out)  x_out[i]  = fmaxf(hn, 0.f);
        if (h_copy) h_copy[i] = hn;
    }
}

__global__ void logits_kernel(const float* __restrict__ out_w,
                              const float* __restrict__ out_b,
                              const float* __restrict__ h,
                              float* __restrict__ out,
                              float* __restrict__ partials) {
    __shared__ __align__(16) float s_h[H];
    __shared__ float s_part[4];
    const int tid = threadIdx.x;
    ((float4*)s_h)[tid] = ((const float4*)h)[tid];
    __syncthreads();

    const int wave = tid >> 6, lane = tid & 63;
    const float4* h4 = (const float4*)s_h;
    const int v0 = blockIdx.x * 8 + wave * 2;
    const int v1 = v0 + 1;
    float acc0 = 0.f, acc1 = 0.f;
    const float4* w0 = (const float4*)(out_w + (size_t)v0 * H);
    const float4* w1 = (const float4*)(out_w + (size_t)v1 * H);
    if (v1 < V) {
        #pragma unroll
        for (int kk = 0; kk < 4; ++kk) {
            int k = kk * 64 + lane;
            float4 b = h4[k];
            float4 a0 = w0[k], a1 = w1[k];
            acc0 += a0.x * b.x + a0.y * b.y + a0.z * b.z + a0.w * b.w;
            acc1 += a1.x * b.x + a1.y * b.y + a1.z * b.z + a1.w * b.w;
        }
    } else if (v0 < V) {
        #pragma unroll
        for (int kk = 0; kk < 4; ++kk) {
            int k = kk * 64 + lane;
            float4 b = h4[k];
            float4 a0 = w0[k];
            acc0 += a0.x * b.x + a0.y * b.y + a0.z * b.z + a0.w * b.w;
        }
    }
    #pragma unroll
    for (int off = 32; off; off >>= 1) {
        acc0 += __shfl_down(acc0, off);
        acc1 += __shfl_down(acc1, off);
    }
    float psum = 0.f;
    if (lane == 0) {
        if (v0 < V) { float lg = acc0 + out_b[v0]; out[v0] = lg; psum += expf(lg); }
        if (v1 < V) { float lg = acc1 + out_b[v1]; out[v1] = lg; psum += expf(lg); }
        s_part[wave] = psum;
    }
    __syncthreads();
    if (tid == 0)
        partials[blockIdx.x] = s_part[0] + s_part[1] + s_part[2] + s_part[3];
}

__global__ void lse_kernel(const float* __restrict__ partials, int n,
                           float* __restrict__ lse) {
    __shared__ float red[256];
    const int tid = threadIdx.x;
    float s = 0.f;
    for (int i = tid; i < n; i += 256) s += partials[i];
    red[tid] = s;
    __syncthreads();
    for (int off = 128; off; off >>= 1) {
        if (tid < off) red[tid] += red[tid + off];
        __syncthreads();
    }
    if (tid == 0) *lse = logf(red[0]);
}

__global__ void sub_kernel(float* __restrict__ out,
                           const float* __restrict__ lse) {
    const int v = blockIdx.x * 256 + threadIdx.x;
    if (v < V) out[v] -= *lse;
}

// ---------------------------------------------------------------------------
extern "C" void kernel_launch(void* const* d_in, const int* in_sizes, int n_in,
                              void* d_out, int out_size, void* d_ws, size_t ws_size,
                              hipStream_t stream) {
    const int*   input_ids = (const int*)d_in[0];
    const float* hidden    = (const float*)d_in[1];
    const float* enc       = (const float*)d_in[2];
    const float* emb       = (const float*)d_in[3];
    const float* attn_w    = (const float*)d_in[4];
    const float* attn_b    = (const float*)d_in[5];
    const float* comb_w    = (const float*)d_in[6];
    const float* comb_b    = (const float*)d_in[7];
    const float* w_ih      = (const float*)d_in[8];
    const float* w_hh      = (const float*)d_in[9];
    const float* b_ih      = (const float*)d_in[10];
    const float* b_hh      = (const float*)d_in[11];
    const float* out_w     = (const float*)d_in[12];
    const float* out_b     = (const float*)d_in[13];

    float* out = (float*)d_out;            // [V | H | L]
    float* ws  = (float*)d_ws;

    // ---- preferred path: single cooperative kernel ----
    FusedArgs args = { input_ids, hidden, enc, emb, attn_w, attn_b,
                       comb_w, comb_b, w_ih, w_hh, b_ih, b_hh,
                       out_w, out_b, out, ws };
    void* kp[] = { &args };
    hipError_t err = hipLaunchCooperativeKernel((void*)fused_kernel,
                                                dim3(256), dim3(512),
                                                kp, 0, stream);
    if (err == hipSuccess) return;

    // ---- fallback: legacy 8-kernel chain ----
    float* ws_scores = ws;                 // 64
    float* ws_app    = ws + 64;            // H
    float* ws_x1     = ws_app + H;         // H
    float* ws_h1     = ws_x1 + H;          // H
    float* ws_x2     = ws_h1 + H;          // H
    float* ws_h2     = ws_x2 + H;          // H
    float* ws_part   = ws_h2 + H;          // 6400
    float* ws_lse    = ws_part + 6400;     // 1

    const int nblk_logits = (V + 7) / 8;

    scores_kernel<<<L, 512, 0, stream>>>(input_ids, hidden, emb, attn_w, attn_b,
                                         ws_scores);
    applied_kernel<<<4, 256, 0, stream>>>(ws_scores, enc, ws_app, out + V + H);
    comb_kernel<<<256, 256, 0, stream>>>(comb_w, comb_b, input_ids, emb, ws_app,
                                         ws_x1);
    gru_kernel<<<256, 256, 0, stream>>>(ws_x1, hidden, w_ih, w_hh, b_ih, b_hh,
                                        ws_h1, ws_x2, nullptr);
    gru_kernel<<<256, 256, 0, stream>>>(ws_x2, ws_h1, w_ih, w_hh, b_ih, b_hh,
                                        ws_h2, nullptr, out + V);
    logits_kernel<<<nblk_logits, 256, 0, stream>>>(out_w, out_b, ws_h2,
                                                   out, ws_part);
    lse_kernel<<<1, 256, 0, stream>>>(ws_part, nblk_logits, ws_lse);
    sub_kernel<<<(V + 255) / 256, 256, 0, stream>>>(out, ws_lse);
}

// Round 2
// 496.301 us; speedup vs baseline: 1.1856x; 1.1856x over previous
//
#include <hip/hip_runtime.h>

#define H 1024
#define V 50257
#define L 50

// ---------------------------------------------------------------------------
// Round-2 design notes:
//  - r1 post-mortem: cg::grid_group::sync() costs ~32 us each (253 us kernel
//    with only ~58 us of actual work and 6 syncs; VALUBusy 2%, HBM 6%).
//  - Fixed harness overhead (fills/memsets) ~335 us; legacy 8-kernel chain
//    was only ~96 us. So: minimize ordering cost, keep wide logits dispatch.
//  - This version: coop head kernel (attn+comb+GRUx2) with TWO hand-rolled
//    agent-scope barriers, then legacy wide logits + fused lse/sub.
// ---------------------------------------------------------------------------

__device__ __forceinline__ float wave_reduce(float v) {
    #pragma unroll
    for (int off = 32; off; off >>= 1) v += __shfl_down(v, off);
    return v;
}

__device__ __forceinline__ float dot4(float4 a, float4 b) {
    return a.x * b.x + a.y * b.y + a.z * b.z + a.w * b.w;
}

// ---- lightweight grid barrier (device globals: immune to ws poisoning; ----
// ---- generation-based: works from any persisted start value)          ----
__device__ unsigned g_cnt = 0;
__device__ unsigned g_gen = 0;

__device__ __forceinline__ void grid_bar() {
    __syncthreads();
    if (threadIdx.x == 0) {
        unsigned g0 = __hip_atomic_load(&g_gen, __ATOMIC_RELAXED,
                                        __HIP_MEMORY_SCOPE_AGENT);
        unsigned old = __hip_atomic_fetch_add(&g_cnt, 1u, __ATOMIC_ACQ_REL,
                                              __HIP_MEMORY_SCOPE_AGENT);
        if (old == gridDim.x - 1) {
            __hip_atomic_store(&g_cnt, 0u, __ATOMIC_RELAXED,
                               __HIP_MEMORY_SCOPE_AGENT);
            __hip_atomic_fetch_add(&g_gen, 1u, __ATOMIC_ACQ_REL,
                                   __HIP_MEMORY_SCOPE_AGENT);
        } else {
            while (__hip_atomic_load(&g_gen, __ATOMIC_RELAXED,
                                     __HIP_MEMORY_SCOPE_AGENT) == g0)
                __builtin_amdgcn_s_sleep(8);
            (void)__hip_atomic_load(&g_gen, __ATOMIC_ACQUIRE,
                                    __HIP_MEMORY_SCOPE_AGENT);
        }
    }
    __syncthreads();
}

struct HeadArgs {
    const int*   input_ids;
    const float* hidden;
    const float* enc;
    const float* emb;
    const float* attn_w;
    const float* attn_b;
    const float* comb_w;
    const float* comb_b;
    const float* w_ih;
    const float* w_hh;
    const float* b_ih;
    const float* b_hh;
    float*       out;     // [V | H | L]
    float*       ws_x1;
    float*       ws_h1;
    float*       ws_x2;
    float*       ws_h2;
};

// ---------------------------------------------------------------------------
// head_kernel: 256 blocks x 512 threads (co-resident, 1 block/CU).
// Phase A (no grid barrier): scores (redundant per block, L2-hot attn_w)
//   -> softmax (redundant per thread) -> applied (redundant, L2-hot enc)
//   -> comb rows bid*4+wave.  Then BAR, GRU1, BAR, GRU2.  Kernel end is the
//   sync point before the wide logits dispatch.
// ---------------------------------------------------------------------------
__global__ void __launch_bounds__(512, 2) head_kernel(HeadArgs a) {
    __shared__ __align__(16) float s_cat[2 * H];  // [emb | h0] -> [emb | applied]
    __shared__ float s_sc[64];                    // 50 scores
    __shared__ __align__(16) float s_x[H];
    __shared__ __align__(16) float s_h[H];
    __shared__ float s_g[4][6];

    const int tid  = threadIdx.x;                 // 512
    const int bid  = blockIdx.x;                  // 256
    const int wave = tid >> 6, lane = tid & 63;
    const int token = a.input_ids[0];

    // ---- stage concat [emb_row | h0] (512 x float4) ------------------------
    ((float4*)s_cat)[tid] = (tid < 256)
        ? ((const float4*)(a.emb + (size_t)token * H))[tid]
        : ((const float4*)a.hidden)[tid - 256];
    __syncthreads();

    // ---- scores: 8 waves strided over 50 rows (attn_w is L2-hot) -----------
    for (int l = wave; l < L; l += 8) {
        const float4* w4 = (const float4*)(a.attn_w + (size_t)l * 2 * H);
        const float4* c4 = (const float4*)s_cat;
        float acc = 0.f;
        #pragma unroll
        for (int kk = 0; kk < 8; ++kk) {
            int k = kk * 64 + lane;
            acc += dot4(w4[k], c4[k]);
        }
        acc = wave_reduce(acc);
        if (lane == 0) s_sc[l] = acc + a.attn_b[l];
    }
    __syncthreads();

    // ---- softmax (redundant/thread) + applied (2 cols/thread) --------------
    {
        float m = s_sc[0];
        #pragma unroll
        for (int l = 1; l < L; ++l) m = fmaxf(m, s_sc[l]);
        float ssum = 0.f;
        #pragma unroll
        for (int l = 0; l < L; ++l) ssum += expf(s_sc[l] - m);
        float inv = 1.f / ssum;
        float acc0 = 0.f, acc1 = 0.f;
        #pragma unroll
        for (int l = 0; l < L; ++l) {
            float wl = expf(s_sc[l] - m) * inv;
            acc0 += wl * a.enc[l * H + tid];
            acc1 += wl * a.enc[l * H + 512 + tid];
        }
        if (bid == 0 && tid < L) a.out[V + H + tid] = expf(s_sc[tid] - m) * inv;
        // overwrite hi half of s_cat with applied (scores already consumed h0)
        s_cat[H + tid]       = acc0;
        s_cat[H + 512 + tid] = acc1;
    }
    __syncthreads();

    // ---- comb: waves 0..3, row i = bid*4 + wave (legacy accumulation order)
    if (wave < 4) {
        const int i = bid * 4 + wave;             // 0..1023
        const float4* r4 = (const float4*)(a.comb_w + (size_t)i * 2 * H);
        const float4* c4 = (const float4*)s_cat;
        float acc = 0.f;
        #pragma unroll
        for (int kk = 0; kk < 8; ++kk) {
            int k = kk * 64 + lane;
            acc += dot4(r4[k], c4[k]);
        }
        acc = wave_reduce(acc);
        if (lane == 0) a.ws_x1[i] = fmaxf(acc + a.comb_b[i], 0.f);
    }
    grid_bar();   // barrier #1

    // ---- GRU x2 (verified r1 structure: 24 gate-dots over 8 waves) ---------
    for (int layer = 0; layer < 2; ++layer) {
        const float* xg = layer ? a.ws_x2 : a.ws_x1;
        const float* hg = layer ? a.ws_h1 : a.hidden;
        if (tid < 256) ((float4*)s_x)[tid]       = ((const float4*)xg)[tid];
        else           ((float4*)s_h)[tid - 256] = ((const float4*)hg)[tid - 256];
        __syncthreads();
        #pragma unroll
        for (int q = 0; q < 3; ++q) {
            const int t = wave * 3 + q;           // 0..23
            const int r = t / 6, g = t % 6;
            const int i = bid * 4 + r;
            const float4* w4 = (const float4*)((g < 3)
                ? (a.w_ih + (size_t)(g * H + i) * H)
                : (a.w_hh + (size_t)((g - 3) * H + i) * H));
            const float4* v4 = (const float4*)((g < 3) ? s_x : s_h);
            float acc = 0.f;
            #pragma unroll
            for (int kk = 0; kk < 4; ++kk) {
                int k = kk * 64 + lane;
                acc += dot4(w4[k], v4[k]);
            }
            acc = wave_reduce(acc);
            if (lane == 0) s_g[r][g] = acc;
        }
        __syncthreads();
        if (tid < 4) {
            const int r = tid, i = bid * 4 + r;
            float gxr = s_g[r][0] + a.b_ih[i];         float ghr = s_g[r][3] + a.b_hh[i];
            float gxz = s_g[r][1] + a.b_ih[H + i];     float ghz = s_g[r][4] + a.b_hh[H + i];
            float gxn = s_g[r][2] + a.b_ih[2 * H + i]; float ghn = s_g[r][5] + a.b_hh[2 * H + i];
            float rr = 1.f / (1.f + expf(-(gxr + ghr)));
            float zz = 1.f / (1.f + expf(-(gxz + ghz)));
            float nn = tanhf(gxn + rr * ghn);
            float hn = (1.f - zz) * nn + zz * s_h[i];
            if (layer == 0) { a.ws_h1[i] = hn; a.ws_x2[i] = fmaxf(hn, 0.f); }
            else            { a.ws_h2[i] = hn; a.out[V + i] = hn; }
        }
        if (layer == 0) grid_bar();   // barrier #2 (kernel end syncs layer 1)
    }
}

// ---------------------------------------------------------------------------
// logits: wide legacy dispatch (6283 x 256) — proven fast, full occupancy.
// ---------------------------------------------------------------------------
__global__ void logits_kernel(const float* __restrict__ out_w,
                              const float* __restrict__ out_b,
                              const float* __restrict__ h,
                              float* __restrict__ out,
                              float* __restrict__ partials) {
    __shared__ __align__(16) float s_h[H];
    __shared__ float s_part[4];
    const int tid = threadIdx.x;
    ((float4*)s_h)[tid] = ((const float4*)h)[tid];
    __syncthreads();

    const int wave = tid >> 6, lane = tid & 63;
    const float4* h4 = (const float4*)s_h;
    const int v0 = blockIdx.x * 8 + wave * 2;
    const int v1 = v0 + 1;
    float acc0 = 0.f, acc1 = 0.f;
    const float4* w0 = (const float4*)(out_w + (size_t)v0 * H);
    const float4* w1 = (const float4*)(out_w + (size_t)v1 * H);
    if (v1 < V) {
        #pragma unroll
        for (int kk = 0; kk < 4; ++kk) {
            int k = kk * 64 + lane;
            float4 b = h4[k];
            float4 a0 = w0[k], a1 = w1[k];
            acc0 += a0.x * b.x + a0.y * b.y + a0.z * b.z + a0.w * b.w;
            acc1 += a1.x * b.x + a1.y * b.y + a1.z * b.z + a1.w * b.w;
        }
    } else if (v0 < V) {
        #pragma unroll
        for (int kk = 0; kk < 4; ++kk) {
            int k = kk * 64 + lane;
            float4 b = h4[k];
            float4 a0 = w0[k];
            acc0 += a0.x * b.x + a0.y * b.y + a0.z * b.z + a0.w * b.w;
        }
    }
    #pragma unroll
    for (int off = 32; off; off >>= 1) {
        acc0 += __shfl_down(acc0, off);
        acc1 += __shfl_down(acc1, off);
    }
    float psum = 0.f;
    if (lane == 0) {
        if (v0 < V) { float lg = acc0 + out_b[v0]; out[v0] = lg; psum += expf(lg); }
        if (v1 < V) { float lg = acc1 + out_b[v1]; out[v1] = lg; psum += expf(lg); }
        s_part[wave] = psum;
    }
    __syncthreads();
    if (tid == 0)
        partials[blockIdx.x] = s_part[0] + s_part[1] + s_part[2] + s_part[3];
}

// ---------------------------------------------------------------------------
// fused lse + subtract: every block redundantly reduces the partials
// (identical order to legacy lse_kernel -> identical numerics), then
// subtracts for its V-chunk. 197 blocks x 256.
// ---------------------------------------------------------------------------
__global__ void sublse_kernel(const float* __restrict__ partials, int n,
                              float* __restrict__ out) {
    __shared__ float red[256];
    const int tid = threadIdx.x;
    float s = 0.f;
    for (int i = tid; i < n; i += 256) s += partials[i];
    red[tid] = s;
    __syncthreads();
    for (int off = 128; off; off >>= 1) {
        if (tid < off) red[tid] += red[tid + off];
        __syncthreads();
    }
    const float lse = logf(red[0]);
    const int v = blockIdx.x * 256 + tid;
    if (v < V) out[v] -= lse;
}

// ===========================================================================
// Legacy 8-kernel fallback (verified) — used only if coop launch is rejected.
// ===========================================================================

__global__ void scores_kernel(const int* __restrict__ input_ids,
                              const float* __restrict__ hidden,
                              const float* __restrict__ emb,
                              const float* __restrict__ attn_w,
                              const float* __restrict__ attn_b,
                              float* __restrict__ ws_scores) {
    __shared__ float s_part[8];
    const int tid = threadIdx.x;
    const int l   = blockIdx.x;
    const int wave = tid >> 6, lane = tid & 63;
    const int token = input_ids[0];

    float4 a = ((const float4*)(attn_w + (size_t)l * 2 * H))[tid];
    float4 x = (tid < 256) ? ((const float4*)(emb + (size_t)token * H))[tid]
                           : ((const float4*)hidden)[tid - 256];
    float acc = a.x * x.x + a.y * x.y + a.z * x.z + a.w * x.w;
    #pragma unroll
    for (int off = 32; off; off >>= 1) acc += __shfl_down(acc, off);
    if (lane == 0) s_part[wave] = acc;
    __syncthreads();
    if (tid == 0) {
        float s = 0.f;
        #pragma unroll
        for (int w = 0; w < 8; ++w) s += s_part[w];
        ws_scores[l] = s + attn_b[l];
    }
}

__global__ void applied_kernel(const float* __restrict__ ws_scores,
                               const float* __restrict__ enc,
                               float* __restrict__ ws_app,
                               float* __restrict__ out_attnw) {
    const int j = blockIdx.x * 256 + threadIdx.x;
    float w[L];
    float m = ws_scores[0];
    #pragma unroll
    for (int l = 1; l < L; ++l) m = fmaxf(m, ws_scores[l]);
    float s = 0.f;
    #pragma unroll
    for (int l = 0; l < L; ++l) { w[l] = expf(ws_scores[l] - m); s += w[l]; }
    float inv = 1.f / s;
    float acc = 0.f;
    #pragma unroll
    for (int l = 0; l < L; ++l) { w[l] *= inv; acc += w[l] * enc[l * H + j]; }
    ws_app[j] = acc;
    if (blockIdx.x == 0 && threadIdx.x < L) out_attnw[threadIdx.x] = w[threadIdx.x];
}

__global__ void comb_kernel(const float* __restrict__ comb_w,
                            const float* __restrict__ comb_b,
                            const int* __restrict__ input_ids,
                            const float* __restrict__ emb,
                            const float* __restrict__ applied,
                            float* __restrict__ x1) {
    __shared__ __align__(16) float s_c[2 * H];
    const int tid = threadIdx.x;
    const int token = input_ids[0];
    ((float4*)s_c)[tid] = ((const float4*)(emb + (size_t)token * H))[tid];
    ((float4*)(s_c + H))[tid] = ((const float4*)applied)[tid];
    __syncthreads();

    const int wave = tid >> 6, lane = tid & 63;
    const int i = blockIdx.x * 4 + wave;
    const float4* r4 = (const float4*)(comb_w + (size_t)i * 2 * H);
    const float4* c4 = (const float4*)s_c;
    float acc = 0.f;
    #pragma unroll
    for (int kk = 0; kk < 8; ++kk) {
        int k = kk * 64 + lane;
        float4 a = r4[k], b = c4[k];
        acc += a.x * b.x + a.y * b.y + a.z * b.z + a.w * b.w;
    }
    #pragma unroll
    for (int off = 32; off; off >>= 1) acc += __shfl_down(acc, off);
    if (lane == 0) x1[i] = fmaxf(acc + comb_b[i], 0.f);
}

__global__ void gru_kernel(const float* __restrict__ x,
                           const float* __restrict__ hprev,
                           const float* __restrict__ w_ih,
                           const float* __restrict__ w_hh,
                           const float* __restrict__ b_ih,
                           const float* __restrict__ b_hh,
                           float* __restrict__ h_out,
                           float* __restrict__ x_out,
                           float* __restrict__ h_copy) {
    __shared__ __align__(16) float s_x[H];
    __shared__ __align__(16) float s_h[H];
    const int tid = threadIdx.x;
    ((float4*)s_x)[tid] = ((const float4*)x)[tid];
    ((float4*)s_h)[tid] = ((const float4*)hprev)[tid];
    __syncthreads();

    const int wave = tid >> 6, lane = tid & 63;
    const int i = blockIdx.x * 4 + wave;
    const float4* x4 = (const float4*)s_x;
    const float4* h4 = (const float4*)s_h;
    const float4* wr_x = (const float4*)(w_ih + (size_t)i * H);
    const float4* wz_x = (const float4*)(w_ih + (size_t)(H + i) * H);
    const float4* wn_x = (const float4*)(w_ih + (size_t)(2 * H + i) * H);
    const float4* wr_h = (const float4*)(w_hh + (size_t)i * H);
    const float4* wz_h = (const float4*)(w_hh + (size_t)(H + i) * H);
    const float4* wn_h = (const float4*)(w_hh + (size_t)(2 * H + i) * H);

    float ar = 0.f, az = 0.f, an = 0.f, br = 0.f, bz = 0.f, bn = 0.f;
    #pragma unroll
    for (int kk = 0; kk < 4; ++kk) {
        int k = kk * 64 + lane;
        float4 xv = x4[k], hv = h4[k], t;
        t = wr_x[k]; ar += t.x * xv.x + t.y * xv.y + t.z * xv.z + t.w * xv.w;
        t = wz_x[k]; az += t.x * xv.x + t.y * xv.y + t.z * xv.z + t.w * xv.w;
        t = wn_x[k]; an += t.x * xv.x + t.y * xv.y + t.z * xv.z + t.w * xv.w;
        t = wr_h[k]; br += t.x * hv.x + t.y * hv.y + t.z * hv.z + t.w * hv.w;
        t = wz_h[k]; bz += t.x * hv.x + t.y * hv.y + t.z * hv.z + t.w * hv.w;
        t = wn_h[k]; bn += t.x * hv.x + t.y * hv.y + t.z * hv.z + t.w * hv.w;
    }
    #pragma unroll
    for (int off = 32; off; off >>= 1) {
        ar += __shfl_down(ar, off); az += __shfl_down(az, off);
        an += __shfl_down(an, off); br += __shfl_down(br, off);
        bz += __shfl_down(bz, off); bn += __shfl_down(bn, off);
    }
    if (lane == 0) {
        float gxr = ar + b_ih[i],         ghr = br + b_hh[i];
        float gxz = az + b_ih[H + i],     ghz = bz + b_hh[H + i];
        float gxn = an + b_ih[2 * H + i], ghn = bn + b_hh[2 * H + i];
        float r = 1.f / (1.f + expf(-(gxr + ghr)));
        float z = 1.f / (1.f + expf(-(gxz + ghz)));
        float n = tanhf(gxn + r * ghn);
        float hn = (1.f - z) * n + z * s_h[i];
        h_out[i] = hn;
        if (x_out)  x_out[i]  = fmaxf(hn, 0.f);
        if (h_copy) h_copy[i] = hn;
    }
}

__global__ void lse_kernel(const float* __restrict__ partials, int n,
                           float* __restrict__ lse) {
    __shared__ float red[256];
    const int tid = threadIdx.x;
    float s = 0.f;
    for (int i = tid; i < n; i += 256) s += partials[i];
    red[tid] = s;
    __syncthreads();
    for (int off = 128; off; off >>= 1) {
        if (tid < off) red[tid] += red[tid + off];
        __syncthreads();
    }
    if (tid == 0) *lse = logf(red[0]);
}

__global__ void sub_kernel(float* __restrict__ out,
                           const float* __restrict__ lse) {
    const int v = blockIdx.x * 256 + threadIdx.x;
    if (v < V) out[v] -= *lse;
}

// ---------------------------------------------------------------------------
extern "C" void kernel_launch(void* const* d_in, const int* in_sizes, int n_in,
                              void* d_out, int out_size, void* d_ws, size_t ws_size,
                              hipStream_t stream) {
    const int*   input_ids = (const int*)d_in[0];
    const float* hidden    = (const float*)d_in[1];
    const float* enc       = (const float*)d_in[2];
    const float* emb       = (const float*)d_in[3];
    const float* attn_w    = (const float*)d_in[4];
    const float* attn_b    = (const float*)d_in[5];
    const float* comb_w    = (const float*)d_in[6];
    const float* comb_b    = (const float*)d_in[7];
    const float* w_ih      = (const float*)d_in[8];
    const float* w_hh      = (const float*)d_in[9];
    const float* b_ih      = (const float*)d_in[10];
    const float* b_hh      = (const float*)d_in[11];
    const float* out_w     = (const float*)d_in[12];
    const float* out_b     = (const float*)d_in[13];

    float* out = (float*)d_out;            // [V | H | L]
    float* ws  = (float*)d_ws;
    float* ws_scores = ws;                 // 64
    float* ws_app    = ws + 64;            // H
    float* ws_x1     = ws_app + H;         // H
    float* ws_h1     = ws_x1 + H;          // H
    float* ws_x2     = ws_h1 + H;          // H
    float* ws_h2     = ws_x2 + H;          // H
    float* ws_part   = ws_h2 + H;          // 6400
    float* ws_lse    = ws_part + 6400;     // 1

    const int nblk_logits = (V + 7) / 8;   // 6283

    // ---- preferred path: coop head (2 custom barriers) + wide logits ------
    HeadArgs hargs = { input_ids, hidden, enc, emb, attn_w, attn_b,
                       comb_w, comb_b, w_ih, w_hh, b_ih, b_hh,
                       out, ws_x1, ws_h1, ws_x2, ws_h2 };
    void* kp[] = { &hargs };
    hipError_t err = hipLaunchCooperativeKernel((void*)head_kernel,
                                                dim3(256), dim3(512),
                                                kp, 0, stream);
    if (err == hipSuccess) {
        logits_kernel<<<nblk_logits, 256, 0, stream>>>(out_w, out_b, ws_h2,
                                                       out, ws_part);
        sublse_kernel<<<(V + 255) / 256, 256, 0, stream>>>(ws_part, nblk_logits,
                                                           out);
        return;
    }
    (void)hipGetLastError();   // clear error state, fall back

    // ---- fallback: legacy 8-kernel chain ----------------------------------
    scores_kernel<<<L, 512, 0, stream>>>(input_ids, hidden, emb, attn_w, attn_b,
                                         ws_scores);
    applied_kernel<<<4, 256, 0, stream>>>(ws_scores, enc, ws_app, out + V + H);
    comb_kernel<<<256, 256, 0, stream>>>(comb_w, comb_b, input_ids, emb, ws_app,
                                         ws_x1);
    gru_kernel<<<256, 256, 0, stream>>>(ws_x1, hidden, w_ih, w_hh, b_ih, b_hh,
                                        ws_h1, ws_x2, nullptr);
    gru_kernel<<<256, 256, 0, stream>>>(ws_x2, ws_h1, w_ih, w_hh, b_ih, b_hh,
                                        ws_h2, nullptr, out + V);
    logits_kernel<<<nblk_logits, 256, 0, stream>>>(out_w, out_b, ws_h2,
                                                   out, ws_part);
    lse_kernel<<<1, 256, 0, stream>>>(ws_part, nblk_logits, ws_lse);
    sub_kernel<<<(V + 255) / 256, 256, 0, stream>>>(out, ws_lse);
}

// Round 3
// 435.608 us; speedup vs baseline: 1.3508x; 1.1393x over previous
//
#include <hip/hip_runtime.h>

#define H 1024
#define V 50257
#define L 50

// ---------------------------------------------------------------------------
// Round-3 design notes (calibrated):
//  - Fixed harness overhead = ~335 us (fills/memsets), invariant across r0-r2.
//  - Grid barriers cost 30-50 us EACH on MI355X (both cg::sync and hand-rolled
//    agent-scope atomics: cross-XCD L2 wb/inv dominates). Coop launch adds
//    drain overhead too. Plain launch boundaries cost only ~5 us.
//  => Strategy: NO grid barriers, NO coop launch. Cut launches 8 -> 5:
//     1. head_kernel  = scores+softmax+applied+comb (per-block redundant,
//        no cross-block deps; verified bit-exact in r2)
//     2. gru_kernel   (layer 1, verified)
//     3. gru_kernel   (layer 2, verified)
//     4. logits_kernel (verified, HBM-bound ~30 us floor)
//     5. sublse_kernel (fused lse+subtract, verified in r2)
// ---------------------------------------------------------------------------

__device__ __forceinline__ float wave_reduce(float v) {
    #pragma unroll
    for (int off = 32; off; off >>= 1) v += __shfl_down(v, off);
    return v;
}

__device__ __forceinline__ float dot4(float4 a, float4 b) {
    return a.x * b.x + a.y * b.y + a.z * b.z + a.w * b.w;
}

// ---------------------------------------------------------------------------
// head_kernel: 256 blocks x 512 threads, plain launch, no grid deps.
// Each block redundantly computes scores (attn_w is L2-hot per XCD, 0.4 MB),
// softmax (per thread), applied (enc L2-hot, 0.2 MB), then its own 4 comb
// rows i = bid*4 + wave. Code identical to r2's verified phase A.
// ---------------------------------------------------------------------------
__global__ void __launch_bounds__(512) head_kernel(
        const int* __restrict__ input_ids,
        const float* __restrict__ hidden,
        const float* __restrict__ enc,
        const float* __restrict__ emb,
        const float* __restrict__ attn_w,
        const float* __restrict__ attn_b,
        const float* __restrict__ comb_w,
        const float* __restrict__ comb_b,
        float* __restrict__ out_attnw,   // out + V + H
        float* __restrict__ ws_x1) {
    __shared__ __align__(16) float s_cat[2 * H];  // [emb | h0] -> [emb | applied]
    __shared__ float s_sc[64];                    // 50 scores

    const int tid  = threadIdx.x;                 // 512
    const int bid  = blockIdx.x;                  // 256
    const int wave = tid >> 6, lane = tid & 63;
    const int token = input_ids[0];

    // ---- stage concat [emb_row | h0] (512 x float4) ------------------------
    ((float4*)s_cat)[tid] = (tid < 256)
        ? ((const float4*)(emb + (size_t)token * H))[tid]
        : ((const float4*)hidden)[tid - 256];
    __syncthreads();

    // ---- scores: 8 waves strided over 50 rows ------------------------------
    for (int l = wave; l < L; l += 8) {
        const float4* w4 = (const float4*)(attn_w + (size_t)l * 2 * H);
        const float4* c4 = (const float4*)s_cat;
        float acc = 0.f;
        #pragma unroll
        for (int kk = 0; kk < 8; ++kk) {
            int k = kk * 64 + lane;
            acc += dot4(w4[k], c4[k]);
        }
        acc = wave_reduce(acc);
        if (lane == 0) s_sc[l] = acc + attn_b[l];
    }
    __syncthreads();

    // ---- softmax (redundant/thread) + applied (2 cols/thread) --------------
    {
        float m = s_sc[0];
        #pragma unroll
        for (int l = 1; l < L; ++l) m = fmaxf(m, s_sc[l]);
        float ssum = 0.f;
        #pragma unroll
        for (int l = 0; l < L; ++l) ssum += expf(s_sc[l] - m);
        float inv = 1.f / ssum;
        float acc0 = 0.f, acc1 = 0.f;
        #pragma unroll
        for (int l = 0; l < L; ++l) {
            float wl = expf(s_sc[l] - m) * inv;
            acc0 += wl * enc[l * H + tid];
            acc1 += wl * enc[l * H + 512 + tid];
        }
        if (bid == 0 && tid < L) out_attnw[tid] = expf(s_sc[tid] - m) * inv;
        // overwrite hi half of s_cat with applied (scores already consumed h0)
        s_cat[H + tid]       = acc0;
        s_cat[H + 512 + tid] = acc1;
    }
    __syncthreads();

    // ---- comb: waves 0..3, row i = bid*4 + wave ----------------------------
    if (wave < 4) {
        const int i = bid * 4 + wave;             // 0..1023
        const float4* r4 = (const float4*)(comb_w + (size_t)i * 2 * H);
        const float4* c4 = (const float4*)s_cat;
        float acc = 0.f;
        #pragma unroll
        for (int kk = 0; kk < 8; ++kk) {
            int k = kk * 64 + lane;
            acc += dot4(r4[k], c4[k]);
        }
        acc = wave_reduce(acc);
        if (lane == 0) ws_x1[i] = fmaxf(acc + comb_b[i], 0.f);
    }
}

// ---------------------------------------------------------------------------
// gru_kernel: verified legacy. Wave owns row i, computes all 6 gate dots.
// ---------------------------------------------------------------------------
__global__ void gru_kernel(const float* __restrict__ x,
                           const float* __restrict__ hprev,
                           const float* __restrict__ w_ih,
                           const float* __restrict__ w_hh,
                           const float* __restrict__ b_ih,
                           const float* __restrict__ b_hh,
                           float* __restrict__ h_out,
                           float* __restrict__ x_out,   // relu(h), nullable
                           float* __restrict__ h_copy)  // mirror, nullable
{
    __shared__ __align__(16) float s_x[H];
    __shared__ __align__(16) float s_h[H];
    const int tid = threadIdx.x;
    ((float4*)s_x)[tid] = ((const float4*)x)[tid];
    ((float4*)s_h)[tid] = ((const float4*)hprev)[tid];
    __syncthreads();

    const int wave = tid >> 6, lane = tid & 63;
    const int i = blockIdx.x * 4 + wave;
    const float4* x4 = (const float4*)s_x;
    const float4* h4 = (const float4*)s_h;
    const float4* wr_x = (const float4*)(w_ih + (size_t)i * H);
    const float4* wz_x = (const float4*)(w_ih + (size_t)(H + i) * H);
    const float4* wn_x = (const float4*)(w_ih + (size_t)(2 * H + i) * H);
    const float4* wr_h = (const float4*)(w_hh + (size_t)i * H);
    const float4* wz_h = (const float4*)(w_hh + (size_t)(H + i) * H);
    const float4* wn_h = (const float4*)(w_hh + (size_t)(2 * H + i) * H);

    float ar = 0.f, az = 0.f, an = 0.f, br = 0.f, bz = 0.f, bn = 0.f;
    #pragma unroll
    for (int kk = 0; kk < 4; ++kk) {
        int k = kk * 64 + lane;
        float4 xv = x4[k], hv = h4[k], t;
        t = wr_x[k]; ar += t.x * xv.x + t.y * xv.y + t.z * xv.z + t.w * xv.w;
        t = wz_x[k]; az += t.x * xv.x + t.y * xv.y + t.z * xv.z + t.w * xv.w;
        t = wn_x[k]; an += t.x * xv.x + t.y * xv.y + t.z * xv.z + t.w * xv.w;
        t = wr_h[k]; br += t.x * hv.x + t.y * hv.y + t.z * hv.z + t.w * hv.w;
        t = wz_h[k]; bz += t.x * hv.x + t.y * hv.y + t.z * hv.z + t.w * hv.w;
        t = wn_h[k]; bn += t.x * hv.x + t.y * hv.y + t.z * hv.z + t.w * hv.w;
    }
    #pragma unroll
    for (int off = 32; off; off >>= 1) {
        ar += __shfl_down(ar, off); az += __shfl_down(az, off);
        an += __shfl_down(an, off); br += __shfl_down(br, off);
        bz += __shfl_down(bz, off); bn += __shfl_down(bn, off);
    }
    if (lane == 0) {
        float gxr = ar + b_ih[i],         ghr = br + b_hh[i];
        float gxz = az + b_ih[H + i],     ghz = bz + b_hh[H + i];
        float gxn = an + b_ih[2 * H + i], ghn = bn + b_hh[2 * H + i];
        float r = 1.f / (1.f + expf(-(gxr + ghr)));
        float z = 1.f / (1.f + expf(-(gxz + ghz)));
        float n = tanhf(gxn + r * ghn);
        float hn = (1.f - z) * n + z * s_h[i];
        h_out[i] = hn;
        if (x_out)  x_out[i]  = fmaxf(hn, 0.f);
        if (h_copy) h_copy[i] = hn;
    }
}

// ---------------------------------------------------------------------------
// logits: verified legacy wide dispatch (6283 x 256), HBM-bound.
// ---------------------------------------------------------------------------
__global__ void logits_kernel(const float* __restrict__ out_w,
                              const float* __restrict__ out_b,
                              const float* __restrict__ h,
                              float* __restrict__ out,
                              float* __restrict__ partials) {
    __shared__ __align__(16) float s_h[H];
    __shared__ float s_part[4];
    const int tid = threadIdx.x;
    ((float4*)s_h)[tid] = ((const float4*)h)[tid];
    __syncthreads();

    const int wave = tid >> 6, lane = tid & 63;
    const float4* h4 = (const float4*)s_h;
    const int v0 = blockIdx.x * 8 + wave * 2;
    const int v1 = v0 + 1;
    float acc0 = 0.f, acc1 = 0.f;
    const float4* w0 = (const float4*)(out_w + (size_t)v0 * H);
    const float4* w1 = (const float4*)(out_w + (size_t)v1 * H);
    if (v1 < V) {
        #pragma unroll
        for (int kk = 0; kk < 4; ++kk) {
            int k = kk * 64 + lane;
            float4 b = h4[k];
            float4 a0 = w0[k], a1 = w1[k];
            acc0 += a0.x * b.x + a0.y * b.y + a0.z * b.z + a0.w * b.w;
            acc1 += a1.x * b.x + a1.y * b.y + a1.z * b.z + a1.w * b.w;
        }
    } else if (v0 < V) {
        #pragma unroll
        for (int kk = 0; kk < 4; ++kk) {
            int k = kk * 64 + lane;
            float4 b = h4[k];
            float4 a0 = w0[k];
            acc0 += a0.x * b.x + a0.y * b.y + a0.z * b.z + a0.w * b.w;
        }
    }
    #pragma unroll
    for (int off = 32; off; off >>= 1) {
        acc0 += __shfl_down(acc0, off);
        acc1 += __shfl_down(acc1, off);
    }
    float psum = 0.f;
    if (lane == 0) {
        if (v0 < V) { float lg = acc0 + out_b[v0]; out[v0] = lg; psum += expf(lg); }
        if (v1 < V) { float lg = acc1 + out_b[v1]; out[v1] = lg; psum += expf(lg); }
        s_part[wave] = psum;
    }
    __syncthreads();
    if (tid == 0)
        partials[blockIdx.x] = s_part[0] + s_part[1] + s_part[2] + s_part[3];
}

// ---------------------------------------------------------------------------
// sublse: verified in r2. Every block redundantly reduces the partials
// (identical order to legacy lse_kernel), then subtracts for its V-chunk.
// ---------------------------------------------------------------------------
__global__ void sublse_kernel(const float* __restrict__ partials, int n,
                              float* __restrict__ out) {
    __shared__ float red[256];
    const int tid = threadIdx.x;
    float s = 0.f;
    for (int i = tid; i < n; i += 256) s += partials[i];
    red[tid] = s;
    __syncthreads();
    for (int off = 128; off; off >>= 1) {
        if (tid < off) red[tid] += red[tid + off];
        __syncthreads();
    }
    const float lse = logf(red[0]);
    const int v = blockIdx.x * 256 + tid;
    if (v < V) out[v] -= lse;
}

// ---------------------------------------------------------------------------
extern "C" void kernel_launch(void* const* d_in, const int* in_sizes, int n_in,
                              void* d_out, int out_size, void* d_ws, size_t ws_size,
                              hipStream_t stream) {
    const int*   input_ids = (const int*)d_in[0];
    const float* hidden    = (const float*)d_in[1];
    const float* enc       = (const float*)d_in[2];
    const float* emb       = (const float*)d_in[3];
    const float* attn_w    = (const float*)d_in[4];
    const float* attn_b    = (const float*)d_in[5];
    const float* comb_w    = (const float*)d_in[6];
    const float* comb_b    = (const float*)d_in[7];
    const float* w_ih      = (const float*)d_in[8];
    const float* w_hh      = (const float*)d_in[9];
    const float* b_ih      = (const float*)d_in[10];
    const float* b_hh      = (const float*)d_in[11];
    const float* out_w     = (const float*)d_in[12];
    const float* out_b     = (const float*)d_in[13];

    float* out = (float*)d_out;            // [V | H | L]
    float* ws  = (float*)d_ws;
    float* ws_x1     = ws;                 // H
    float* ws_h1     = ws_x1 + H;          // H
    float* ws_x2     = ws_h1 + H;          // H
    float* ws_h2     = ws_x2 + H;          // H
    float* ws_part   = ws_h2 + H;          // 6400

    const int nblk_logits = (V + 7) / 8;   // 6283

    head_kernel<<<256, 512, 0, stream>>>(input_ids, hidden, enc, emb,
                                         attn_w, attn_b, comb_w, comb_b,
                                         out + V + H, ws_x1);
    gru_kernel<<<256, 256, 0, stream>>>(ws_x1, hidden, w_ih, w_hh, b_ih, b_hh,
                                        ws_h1, ws_x2, nullptr);
    gru_kernel<<<256, 256, 0, stream>>>(ws_x2, ws_h1, w_ih, w_hh, b_ih, b_hh,
                                        ws_h2, nullptr, out + V);
    logits_kernel<<<nblk_logits, 256, 0, stream>>>(out_w, out_b, ws_h2,
                                                   out, ws_part);
    sublse_kernel<<<(V + 255) / 256, 256, 0, stream>>>(ws_part, nblk_logits,
                                                       out);
}

// Round 4
// 433.662 us; speedup vs baseline: 1.3569x; 1.0045x over previous
//
#include <hip/hip_runtime.h>

#define H 1024
#define V 50257
#define L 50

// ---------------------------------------------------------------------------
// Round-4 design notes (calibrated):
//  - Fixed harness overhead ~335 us (fills + tiny resets), invariant r0-r3.
//  - Grid barriers / coop launch: 25-50 us each on MI355X -> banned.
//  - Plain launch boundaries: ~3-4 us each (r0 8-launch vs r3 5-launch ~ equal).
//  - Chain ~100 us; dominant controllable term = logits (206 MB read, 33 us
//    floor at 6.3 TB/s). This round: logits 4-rows/wave + h in VGPRs (no LDS
//    stage/barrier, 16 loads in flight per wave, interleaved reduce chains).
//    Per-logit accumulation order unchanged (bit-identical per value).
// ---------------------------------------------------------------------------

__device__ __forceinline__ float wave_reduce(float v) {
    #pragma unroll
    for (int off = 32; off; off >>= 1) v += __shfl_down(v, off);
    return v;
}

__device__ __forceinline__ float dot4(float4 a, float4 b) {
    return a.x * b.x + a.y * b.y + a.z * b.z + a.w * b.w;
}

// ---------------------------------------------------------------------------
// head_kernel: 256 blocks x 512 threads, plain launch, no grid deps.
// Verified (r2/r3). Redundant scores/softmax/applied per block; 4 comb rows.
// ---------------------------------------------------------------------------
__global__ void __launch_bounds__(512) head_kernel(
        const int* __restrict__ input_ids,
        const float* __restrict__ hidden,
        const float* __restrict__ enc,
        const float* __restrict__ emb,
        const float* __restrict__ attn_w,
        const float* __restrict__ attn_b,
        const float* __restrict__ comb_w,
        const float* __restrict__ comb_b,
        float* __restrict__ out_attnw,   // out + V + H
        float* __restrict__ ws_x1) {
    __shared__ __align__(16) float s_cat[2 * H];  // [emb | h0] -> [emb | applied]
    __shared__ float s_sc[64];                    // 50 scores

    const int tid  = threadIdx.x;                 // 512
    const int bid  = blockIdx.x;                  // 256
    const int wave = tid >> 6, lane = tid & 63;
    const int token = input_ids[0];

    ((float4*)s_cat)[tid] = (tid < 256)
        ? ((const float4*)(emb + (size_t)token * H))[tid]
        : ((const float4*)hidden)[tid - 256];
    __syncthreads();

    for (int l = wave; l < L; l += 8) {
        const float4* w4 = (const float4*)(attn_w + (size_t)l * 2 * H);
        const float4* c4 = (const float4*)s_cat;
        float acc = 0.f;
        #pragma unroll
        for (int kk = 0; kk < 8; ++kk) {
            int k = kk * 64 + lane;
            acc += dot4(w4[k], c4[k]);
        }
        acc = wave_reduce(acc);
        if (lane == 0) s_sc[l] = acc + attn_b[l];
    }
    __syncthreads();

    {
        float m = s_sc[0];
        #pragma unroll
        for (int l = 1; l < L; ++l) m = fmaxf(m, s_sc[l]);
        float ssum = 0.f;
        #pragma unroll
        for (int l = 0; l < L; ++l) ssum += expf(s_sc[l] - m);
        float inv = 1.f / ssum;
        float acc0 = 0.f, acc1 = 0.f;
        #pragma unroll
        for (int l = 0; l < L; ++l) {
            float wl = expf(s_sc[l] - m) * inv;
            acc0 += wl * enc[l * H + tid];
            acc1 += wl * enc[l * H + 512 + tid];
        }
        if (bid == 0 && tid < L) out_attnw[tid] = expf(s_sc[tid] - m) * inv;
        s_cat[H + tid]       = acc0;
        s_cat[H + 512 + tid] = acc1;
    }
    __syncthreads();

    if (wave < 4) {
        const int i = bid * 4 + wave;             // 0..1023
        const float4* r4 = (const float4*)(comb_w + (size_t)i * 2 * H);
        const float4* c4 = (const float4*)s_cat;
        float acc = 0.f;
        #pragma unroll
        for (int kk = 0; kk < 8; ++kk) {
            int k = kk * 64 + lane;
            acc += dot4(r4[k], c4[k]);
        }
        acc = wave_reduce(acc);
        if (lane == 0) ws_x1[i] = fmaxf(acc + comb_b[i], 0.f);
    }
}

// ---------------------------------------------------------------------------
// gru_kernel: verified. Wave owns row i, computes all 6 gate dots.
// ---------------------------------------------------------------------------
__global__ void gru_kernel(const float* __restrict__ x,
                           const float* __restrict__ hprev,
                           const float* __restrict__ w_ih,
                           const float* __restrict__ w_hh,
                           const float* __restrict__ b_ih,
                           const float* __restrict__ b_hh,
                           float* __restrict__ h_out,
                           float* __restrict__ x_out,   // relu(h), nullable
                           float* __restrict__ h_copy)  // mirror, nullable
{
    __shared__ __align__(16) float s_x[H];
    __shared__ __align__(16) float s_h[H];
    const int tid = threadIdx.x;
    ((float4*)s_x)[tid] = ((const float4*)x)[tid];
    ((float4*)s_h)[tid] = ((const float4*)hprev)[tid];
    __syncthreads();

    const int wave = tid >> 6, lane = tid & 63;
    const int i = blockIdx.x * 4 + wave;
    const float4* x4 = (const float4*)s_x;
    const float4* h4 = (const float4*)s_h;
    const float4* wr_x = (const float4*)(w_ih + (size_t)i * H);
    const float4* wz_x = (const float4*)(w_ih + (size_t)(H + i) * H);
    const float4* wn_x = (const float4*)(w_ih + (size_t)(2 * H + i) * H);
    const float4* wr_h = (const float4*)(w_hh + (size_t)i * H);
    const float4* wz_h = (const float4*)(w_hh + (size_t)(H + i) * H);
    const float4* wn_h = (const float4*)(w_hh + (size_t)(2 * H + i) * H);

    float ar = 0.f, az = 0.f, an = 0.f, br = 0.f, bz = 0.f, bn = 0.f;
    #pragma unroll
    for (int kk = 0; kk < 4; ++kk) {
        int k = kk * 64 + lane;
        float4 xv = x4[k], hv = h4[k], t;
        t = wr_x[k]; ar += t.x * xv.x + t.y * xv.y + t.z * xv.z + t.w * xv.w;
        t = wz_x[k]; az += t.x * xv.x + t.y * xv.y + t.z * xv.z + t.w * xv.w;
        t = wn_x[k]; an += t.x * xv.x + t.y * xv.y + t.z * xv.z + t.w * xv.w;
        t = wr_h[k]; br += t.x * hv.x + t.y * hv.y + t.z * hv.z + t.w * hv.w;
        t = wz_h[k]; bz += t.x * hv.x + t.y * hv.y + t.z * hv.z + t.w * hv.w;
        t = wn_h[k]; bn += t.x * hv.x + t.y * hv.y + t.z * hv.z + t.w * hv.w;
    }
    #pragma unroll
    for (int off = 32; off; off >>= 1) {
        ar += __shfl_down(ar, off); az += __shfl_down(az, off);
        an += __shfl_down(an, off); br += __shfl_down(br, off);
        bz += __shfl_down(bz, off); bn += __shfl_down(bn, off);
    }
    if (lane == 0) {
        float gxr = ar + b_ih[i],         ghr = br + b_hh[i];
        float gxz = az + b_ih[H + i],     ghz = bz + b_hh[H + i];
        float gxn = an + b_ih[2 * H + i], ghn = bn + b_hh[2 * H + i];
        float r = 1.f / (1.f + expf(-(gxr + ghr)));
        float z = 1.f / (1.f + expf(-(gxz + ghz)));
        float n = tanhf(gxn + r * ghn);
        float hn = (1.f - z) * n + z * s_h[i];
        h_out[i] = hn;
        if (x_out)  x_out[i]  = fmaxf(hn, 0.f);
        if (h_copy) h_copy[i] = hn;
    }
}

// ---------------------------------------------------------------------------
// logits: 4 rows/wave, h in VGPRs (no LDS stage/barrier before dots).
// Per-logit accumulation order identical to the verified kernel
// (kk ascending, dot4 xyzw). 3142 blocks x 256; 16 rows/block.
// ---------------------------------------------------------------------------
__global__ void __launch_bounds__(256) logits_kernel(
        const float* __restrict__ out_w,
        const float* __restrict__ out_b,
        const float* __restrict__ h,
        float* __restrict__ out,
        float* __restrict__ partials) {
    __shared__ float s_part[4];
    const int tid = threadIdx.x;
    const int wave = tid >> 6, lane = tid & 63;

    const float4* h4 = (const float4*)h;
    const float4 hv0 = h4[lane];
    const float4 hv1 = h4[64 + lane];
    const float4 hv2 = h4[128 + lane];
    const float4 hv3 = h4[192 + lane];

    const int v0 = blockIdx.x * 16 + wave * 4;    // 4 consecutive rows/wave
    // clamped row pointers keep tail loads legal (values discarded)
    const float4* w0 = (const float4*)(out_w + (size_t)((v0     < V) ? v0     : V - 1) * H);
    const float4* w1 = (const float4*)(out_w + (size_t)((v0 + 1 < V) ? v0 + 1 : V - 1) * H);
    const float4* w2 = (const float4*)(out_w + (size_t)((v0 + 2 < V) ? v0 + 2 : V - 1) * H);
    const float4* w3 = (const float4*)(out_w + (size_t)((v0 + 3 < V) ? v0 + 3 : V - 1) * H);

    float acc0 = 0.f, acc1 = 0.f, acc2 = 0.f, acc3 = 0.f;
    #pragma unroll
    for (int kk = 0; kk < 4; ++kk) {
        const int k = kk * 64 + lane;
        const float4 b = (kk == 0) ? hv0 : (kk == 1) ? hv1 : (kk == 2) ? hv2 : hv3;
        float4 a0 = w0[k], a1 = w1[k], a2 = w2[k], a3 = w3[k];
        acc0 += dot4(a0, b);
        acc1 += dot4(a1, b);
        acc2 += dot4(a2, b);
        acc3 += dot4(a3, b);
    }
    #pragma unroll
    for (int off = 32; off; off >>= 1) {
        acc0 += __shfl_down(acc0, off);
        acc1 += __shfl_down(acc1, off);
        acc2 += __shfl_down(acc2, off);
        acc3 += __shfl_down(acc3, off);
    }
    float psum = 0.f;
    if (lane == 0) {
        if (v0     < V) { float lg = acc0 + out_b[v0];     out[v0]     = lg; psum += expf(lg); }
        if (v0 + 1 < V) { float lg = acc1 + out_b[v0 + 1]; out[v0 + 1] = lg; psum += expf(lg); }
        if (v0 + 2 < V) { float lg = acc2 + out_b[v0 + 2]; out[v0 + 2] = lg; psum += expf(lg); }
        if (v0 + 3 < V) { float lg = acc3 + out_b[v0 + 3]; out[v0 + 3] = lg; psum += expf(lg); }
        s_part[wave] = psum;
    }
    __syncthreads();
    if (tid == 0)
        partials[blockIdx.x] = s_part[0] + s_part[1] + s_part[2] + s_part[3];
}

// ---------------------------------------------------------------------------
// sublse: verified (r2/r3). Every block redundantly reduces the partials,
// then subtracts lse for its V-chunk.
// ---------------------------------------------------------------------------
__global__ void sublse_kernel(const float* __restrict__ partials, int n,
                              float* __restrict__ out) {
    __shared__ float red[256];
    const int tid = threadIdx.x;
    float s = 0.f;
    for (int i = tid; i < n; i += 256) s += partials[i];
    red[tid] = s;
    __syncthreads();
    for (int off = 128; off; off >>= 1) {
        if (tid < off) red[tid] += red[tid + off];
        __syncthreads();
    }
    const float lse = logf(red[0]);
    const int v = blockIdx.x * 256 + tid;
    if (v < V) out[v] -= lse;
}

// ---------------------------------------------------------------------------
extern "C" void kernel_launch(void* const* d_in, const int* in_sizes, int n_in,
                              void* d_out, int out_size, void* d_ws, size_t ws_size,
                              hipStream_t stream) {
    const int*   input_ids = (const int*)d_in[0];
    const float* hidden    = (const float*)d_in[1];
    const float* enc       = (const float*)d_in[2];
    const float* emb       = (const float*)d_in[3];
    const float* attn_w    = (const float*)d_in[4];
    const float* attn_b    = (const float*)d_in[5];
    const float* comb_w    = (const float*)d_in[6];
    const float* comb_b    = (const float*)d_in[7];
    const float* w_ih      = (const float*)d_in[8];
    const float* w_hh      = (const float*)d_in[9];
    const float* b_ih      = (const float*)d_in[10];
    const float* b_hh      = (const float*)d_in[11];
    const float* out_w     = (const float*)d_in[12];
    const float* out_b     = (const float*)d_in[13];

    float* out = (float*)d_out;            // [V | H | L]
    float* ws  = (float*)d_ws;
    float* ws_x1     = ws;                 // H
    float* ws_h1     = ws_x1 + H;          // H
    float* ws_x2     = ws_h1 + H;          // H
    float* ws_h2     = ws_x2 + H;          // H
    float* ws_part   = ws_h2 + H;          // 3142

    const int nblk_logits = (V + 15) / 16; // 3142

    head_kernel<<<256, 512, 0, stream>>>(input_ids, hidden, enc, emb,
                                         attn_w, attn_b, comb_w, comb_b,
                                         out + V + H, ws_x1);
    gru_kernel<<<256, 256, 0, stream>>>(ws_x1, hidden, w_ih, w_hh, b_ih, b_hh,
                                        ws_h1, ws_x2, nullptr);
    gru_kernel<<<256, 256, 0, stream>>>(ws_x2, ws_h1, w_ih, w_hh, b_ih, b_hh,
                                        ws_h2, nullptr, out + V);
    logits_kernel<<<nblk_logits, 256, 0, stream>>>(out_w, out_b, ws_h2,
                                                   out, ws_part);
    sublse_kernel<<<(V + 255) / 256, 256, 0, stream>>>(ws_part, nblk_logits,
                                                       out);
}